// Round 12
// baseline (207.383 us; speedup 1.0000x reference)
//
#include <hip/hip_runtime.h>
#include <math.h>

#define NB 32
#define NI 32
#define NA 16
#define NOD 10
#define NOA 16
#define NK 160         // NOD*NOA
#define NHW 144
#define NROUT 3
#define NROWS (NB*NHW) // 4608 pixel-rows
#define SVLD 168       // ushort row stride (336 B, 8B-aligned)

// workspace layout: [w_bf: 81920 ushort = 160KB][pad][x_t: NROWS*512 f32]
#define XT_OFF 262144
#define WS_NEEDED (XT_OFF + (size_t)NROWS * 512 * 4)

// ---- bf16 RNE pack / unpack ----
__device__ __forceinline__ unsigned short f2bf(float f) {
    unsigned b = __builtin_bit_cast(unsigned, f);
    b += 0x7fffu + ((b >> 16) & 1u);
    return (unsigned short)(b >> 16);
}
__device__ __forceinline__ float bf_lo(unsigned d) {
    return __builtin_bit_cast(float, d << 16);
}
__device__ __forceinline__ float bf_hi(unsigned d) {
    return __builtin_bit_cast(float, d & 0xffff0000u);
}

// =====================================================================
// Pre-pass (unchanged): weight f32->bf16; x -> per-block-contiguous
// x_t[b][hw/4][i][a][hw%4].
// =====================================================================
__global__ __launch_bounds__(256)
void prepass_kernel(const float* __restrict__ x,
                    const float* __restrict__ weight,
                    unsigned short* __restrict__ w_bf,
                    float* __restrict__ x_t)
{
    int bid = blockIdx.x;
    const int tid = threadIdx.x;
    if (bid < 320) {
        const int idx = bid * 256 + tid;
        w_bf[idx] = f2bf(weight[idx]);
        return;
    }
    bid -= 320;
    const int b  = bid / 72;
    const int r  = bid % 72;
    const int jt = r / 9;
    const int ht = r % 9;
    const int j0 = jt * 64, hw0 = ht * 16;

    __shared__ float tile[64][17];
    {
        const int hh = tid & 15;
        const int j1 = tid >> 4;
#pragma unroll
        for (int s = 0; s < 4; ++s) {
            const int jj = j1 + s * 16;
            tile[jj][hh] = x[(size_t)b * 73728 + (size_t)(j0 + jj) * NHW + hw0 + hh];
        }
    }
    __syncthreads();
    {
        const int jj = tid >> 2;
        const int p  = tid & 3;
#pragma unroll
        for (int s = 0; s < 4; ++s) {
            const int hwg = ht * 4 + s;
            x_t[((size_t)b * 36 + hwg) * 2048 + (size_t)(j0 + jj) * 4 + p] =
                tile[jj][s * 4 + p];
        }
    }
}

// =====================================================================
// Fused kernel v4.1: 512 thr = 8 waves = 4 rows x 2 od-HALVES.
// R11 v4 + two fixes:
//  (a) bias double-count: i-half lane pair both initialized acc with
//      bias, then pair-summed -> 2x bias. Now hh==0 lane only.
//  (b) slog race: sibling wave's softmax (reads slog of iter t-1) vs
//      this wave's agreement write (iter t) had no cross-wave barrier.
//      The post-softmax barrier is now __syncthreads (uniform it>0).
// =====================================================================
__global__ __launch_bounds__(512, 6)
void capsule_fused4_kernel(const float* __restrict__ x_t,           // [NROWS/4][2048]
                           const unsigned short* __restrict__ w_bf, // [NI*NA*NK]
                           const float* __restrict__ bias,          // [NK]
                           float* __restrict__ out)                 // [B,K,HW]
{
    __shared__ unsigned short sv[4][NI][SVLD];        // 43008 B bf16 votes
    __shared__ __align__(16) float smem[2696];        // 10784 B routing bufs
    float* const slog_f         = smem;                               // [4][10][34] f32
    unsigned short* const srt_h = (unsigned short*)(smem + 1360);     // [4][10][34] bf16
    float* const sact_f         = smem + 2040;                        // [4][164] f32
    float* const xp             = smem;               // x staging (phase 1 only)

    const int tid = threadIdx.x;
    const int wid = tid >> 6;
    const int l   = tid & 63;
    const int w2  = wid >> 1;          // local row 0..3
    const int hf  = wid & 1;           // od/k half
    const int b   = blockIdx.x / (NHW / 4);
    const int hw0 = (blockIdx.x % (NHW / 4)) * 4;

    // ---- phase 1a: contiguous x slice -> xp ([i][a][p] layout) ----
    {
        const float4* src = reinterpret_cast<const float4*>(x_t + (size_t)blockIdx.x * 2048);
        reinterpret_cast<float4*>(xp)[tid] = src[tid];
    }
    __syncthreads();

    // ---- phase 1b: votes. task (i, k-oct): 640 tasks over 512 thr ----
    for (int t = tid; t < NI * 20; t += 512) {
        const int i  = t / 20;
        const int ko = t - i * 20;
        const int k0 = ko * 8;
        const uint4* wp = reinterpret_cast<const uint4*>(w_bf + (size_t)i * NA * NK + k0);
        float4 acc[4][2];
#pragma unroll
        for (int p = 0; p < 4; ++p) {
            acc[p][0] = make_float4(0.f, 0.f, 0.f, 0.f);
            acc[p][1] = make_float4(0.f, 0.f, 0.f, 0.f);
        }
#pragma unroll
        for (int a = 0; a < NA; ++a) {
            const uint4 wv = wp[(size_t)a * 20];
            const float w0 = bf_lo(wv.x), w1 = bf_hi(wv.x);
            const float w2_ = bf_lo(wv.y), w3 = bf_hi(wv.y);
            const float w4 = bf_lo(wv.z), w5 = bf_hi(wv.z);
            const float w6 = bf_lo(wv.w), w7 = bf_hi(wv.w);
            const float4 xa = *reinterpret_cast<const float4*>(&xp[(i * NA + a) * 4]);
            const float xs[4] = {xa.x, xa.y, xa.z, xa.w};
#pragma unroll
            for (int p = 0; p < 4; ++p) {
                const float xv = xs[p];
                acc[p][0].x = fmaf(xv, w0, acc[p][0].x);
                acc[p][0].y = fmaf(xv, w1, acc[p][0].y);
                acc[p][0].z = fmaf(xv, w2_, acc[p][0].z);
                acc[p][0].w = fmaf(xv, w3, acc[p][0].w);
                acc[p][1].x = fmaf(xv, w4, acc[p][1].x);
                acc[p][1].y = fmaf(xv, w5, acc[p][1].y);
                acc[p][1].z = fmaf(xv, w6, acc[p][1].z);
                acc[p][1].w = fmaf(xv, w7, acc[p][1].w);
            }
        }
#pragma unroll
        for (int p = 0; p < 4; ++p) {
            *reinterpret_cast<ushort4*>(&sv[p][i][k0]) =
                make_ushort4(f2bf(acc[p][0].x), f2bf(acc[p][0].y),
                             f2bf(acc[p][0].z), f2bf(acc[p][0].w));
            *reinterpret_cast<ushort4*>(&sv[p][i][k0 + 4]) =
                make_ushort4(f2bf(acc[p][1].x), f2bf(acc[p][1].y),
                             f2bf(acc[p][1].z), f2bf(acc[p][1].w));
        }
    }

    // ---- per-lane routing constants ----
    const int kb = hf * 80;            // k-base of this wave's half
    const int ob = hf * 5;             // od-base
    int kq = 0, hh = 0, odg = 0, kg = 0;
    float4 bq = make_float4(0.f, 0.f, 0.f, 0.f);
    if (l < 40) {                      // preact lane map: (k-quad, i-half)
        kq  = l >> 1;                  // 0..19 (k-quad within half)
        hh  = l & 1;                   // i-half
        odg = ob + (kq >> 2);          // global od of this k-quad
        kg  = kb + kq * 4;             // global k
        if (hh == 0)                   // FIX (a): bias on ONE lane of the
            bq = *reinterpret_cast<const float4*>(bias + kg);  // i-half pair
    }
    const int li = l & 31;

    float lgp[3] = {0.f, 0.f, 0.f};    // logits owned as (odl*32+i) tasks

    __syncthreads();                    // sv complete; xp dead

    for (int it = 0; it < NROUT; ++it) {
        // ---- softmax over all 10 od (iter >= 1; iter0 route = 0.1) ----
        if (it > 0) {
            float e[NOD];
            float m = -1e30f;
#pragma unroll
            for (int od = 0; od < NOD; ++od) {
                e[od] = slog_f[(w2 * NOD + od) * 34 + li];
                m = fmaxf(m, e[od]);
            }
            float s = 0.f;
#pragma unroll
            for (int od = 0; od < NOD; ++od) {
                e[od] = __expf(e[od] - m);
                s += e[od];
            }
            const float inv = 1.f / s;
            if (l < 32) {
#pragma unroll
                for (int odl = 0; odl < 5; ++odl)
                    srt_h[(w2 * NOD + ob + odl) * 34 + li] = f2bf(e[ob + odl] * inv);
            }
            __syncthreads();   // FIX (b): all slog reads done before any
                               // wave's agreement rewrites slog this iter
        }

        // ---- preact + squash: lane = (k-quad, i-half) ----
        if (l < 40) {
            float a0 = bq.x, a1 = bq.y, a2 = bq.z, a3 = bq.w;
            const unsigned short* svb  = &sv[w2][hh * 16][kg];
            const unsigned short* srow = &srt_h[(w2 * NOD + odg) * 34 + hh * 16];
#pragma unroll
            for (int s2 = 0; s2 < 8; ++s2) {
                float r0, r1;
                if (it == 0) {
                    r0 = 0.1f; r1 = 0.1f;
                } else {
                    const unsigned u = *reinterpret_cast<const unsigned*>(srow + 2 * s2);
                    r0 = bf_lo(u); r1 = bf_hi(u);
                }
                const uint2 d0 = *reinterpret_cast<const uint2*>(svb + (2 * s2) * SVLD);
                const uint2 d1 = *reinterpret_cast<const uint2*>(svb + (2 * s2 + 1) * SVLD);
                a0 = fmaf(r0, bf_lo(d0.x), a0);
                a1 = fmaf(r0, bf_hi(d0.x), a1);
                a2 = fmaf(r0, bf_lo(d0.y), a2);
                a3 = fmaf(r0, bf_hi(d0.y), a3);
                a0 = fmaf(r1, bf_lo(d1.x), a0);
                a1 = fmaf(r1, bf_hi(d1.x), a1);
                a2 = fmaf(r1, bf_lo(d1.y), a2);
                a3 = fmaf(r1, bf_hi(d1.y), a3);
            }
            // combine i-halves (lane pairs 2kq | 2kq+1)
            a0 += __shfl_xor(a0, 1, 2);
            a1 += __shfl_xor(a1, 1, 2);
            a2 += __shfl_xor(a2, 1, 2);
            a3 += __shfl_xor(a3, 1, 2);
            // squash over the od's 16 k (4 quads = 8-lane group)
            float ss = a0 * a0 + a1 * a1 + a2 * a2 + a3 * a3;
            ss += __shfl_xor(ss, 2, 8);
            ss += __shfl_xor(ss, 4, 8);
            const float sc = sqrtf(ss) / (1.f + ss);
            if (hh == 0)
                *reinterpret_cast<float4*>(&sact_f[w2 * 164 + kg]) =
                    make_float4(a0 * sc, a1 * sc, a2 * sc, a3 * sc);
        }
        __builtin_amdgcn_wave_barrier();

        if (it < NROUT - 1) {
            // ---- agreement: tasks t = odl*32 + i (own od-half) ----
#pragma unroll
            for (int r = 0; r < 3; ++r) {
                const int t = l + 64 * r;
                if (t < 160) {
                    const int odl = t >> 5;
                    const int i   = t & 31;
                    const int od  = ob + odl;
                    const int kk  = od * 16;
                    const uint4 d0 = *reinterpret_cast<const uint4*>(&sv[w2][i][kk]);
                    const uint4 d1 = *reinterpret_cast<const uint4*>(&sv[w2][i][kk + 8]);
                    const float* ap = &sact_f[w2 * 164 + kk];
                    const float4 c0 = *reinterpret_cast<const float4*>(ap + 0);
                    const float4 c1 = *reinterpret_cast<const float4*>(ap + 4);
                    const float4 c2 = *reinterpret_cast<const float4*>(ap + 8);
                    const float4 c3 = *reinterpret_cast<const float4*>(ap + 12);
                    float acc;
                    acc  = bf_lo(d0.x) * c0.x;
                    acc = fmaf(bf_hi(d0.x), c0.y, acc);
                    acc = fmaf(bf_lo(d0.y), c0.z, acc);
                    acc = fmaf(bf_hi(d0.y), c0.w, acc);
                    acc = fmaf(bf_lo(d0.z), c1.x, acc);
                    acc = fmaf(bf_hi(d0.z), c1.y, acc);
                    acc = fmaf(bf_lo(d0.w), c1.z, acc);
                    acc = fmaf(bf_hi(d0.w), c1.w, acc);
                    acc = fmaf(bf_lo(d1.x), c2.x, acc);
                    acc = fmaf(bf_hi(d1.x), c2.y, acc);
                    acc = fmaf(bf_lo(d1.y), c2.z, acc);
                    acc = fmaf(bf_hi(d1.y), c2.w, acc);
                    acc = fmaf(bf_lo(d1.z), c3.x, acc);
                    acc = fmaf(bf_hi(d1.z), c3.y, acc);
                    acc = fmaf(bf_lo(d1.w), c3.z, acc);
                    acc = fmaf(bf_hi(d1.w), c3.w, acc);
                    lgp[r] += acc;
                    slog_f[(w2 * NOD + od) * 34 + i] = lgp[r];
                }
            }
            __syncthreads();   // logits visible to the sibling half-wave
        }
    }

    // ---- output: float4 across the block's 4 consecutive pixels ----
    __syncthreads();
    if (tid < NK) {
        const float4 v = make_float4(sact_f[0 * 164 + tid], sact_f[1 * 164 + tid],
                                     sact_f[2 * 164 + tid], sact_f[3 * 164 + tid]);
        *reinterpret_cast<float4*>(out + ((size_t)b * NK + tid) * NHW + hw0) = v;
    }
}

// =====================================================================
// Fallback (R8 fused, f32 weight, direct x read) if ws too small.
// =====================================================================
__global__ __launch_bounds__(256)
void capsule_fused_kernel(const float* __restrict__ x,
                          const float* __restrict__ weight,
                          const float* __restrict__ bias,
                          float* __restrict__ out)
{
    __shared__ unsigned short sv[4][NI][SVLD];
    __shared__ __align__(16) float pool[2048];
    float* const srt_f  = pool;
    float* const sact_f = pool + 4 * NOD * 33;

    const int tid = threadIdx.x;
    const int w   = tid >> 6;
    const int l   = tid & 63;
    const int b   = blockIdx.x / (NHW / 4);
    const int hw0 = (blockIdx.x % (NHW / 4)) * 4;

    {
        const float* xb = x + ((size_t)b * NI * NA) * NHW + hw0;
        for (int j = tid; j < NI * NA; j += 256) {
            const float4 v = *reinterpret_cast<const float4*>(xb + (size_t)j * NHW);
            *reinterpret_cast<float4*>(&pool[j * 4]) = v;
        }
    }
    __syncthreads();

    for (int j = tid; j < NI * 40; j += 256) {
        const int i  = j / 40;
        const int kq = j - i * 40;
        const int k0 = kq * 4;
        const float4* wp = reinterpret_cast<const float4*>(weight + (size_t)i * NA * NK + k0);
        float4 a0 = make_float4(0.f,0.f,0.f,0.f), a1 = a0, a2 = a0, a3 = a0;
#pragma unroll
        for (int a = 0; a < NA; ++a) {
            const float4 w4 = wp[(size_t)a * 40];
            const float4 xa = *reinterpret_cast<const float4*>(&pool[(i * NA + a) * 4]);
            a0.x = fmaf(xa.x, w4.x, a0.x); a0.y = fmaf(xa.x, w4.y, a0.y);
            a0.z = fmaf(xa.x, w4.z, a0.z); a0.w = fmaf(xa.x, w4.w, a0.w);
            a1.x = fmaf(xa.y, w4.x, a1.x); a1.y = fmaf(xa.y, w4.y, a1.y);
            a1.z = fmaf(xa.y, w4.z, a1.z); a1.w = fmaf(xa.y, w4.w, a1.w);
            a2.x = fmaf(xa.z, w4.x, a2.x); a2.y = fmaf(xa.z, w4.y, a2.y);
            a2.z = fmaf(xa.z, w4.z, a2.z); a2.w = fmaf(xa.z, w4.w, a2.w);
            a3.x = fmaf(xa.w, w4.x, a3.x); a3.y = fmaf(xa.w, w4.y, a3.y);
            a3.z = fmaf(xa.w, w4.z, a3.z); a3.w = fmaf(xa.w, w4.w, a3.w);
        }
        *reinterpret_cast<ushort4*>(&sv[0][i][k0]) =
            make_ushort4(f2bf(a0.x), f2bf(a0.y), f2bf(a0.z), f2bf(a0.w));
        *reinterpret_cast<ushort4*>(&sv[1][i][k0]) =
            make_ushort4(f2bf(a1.x), f2bf(a1.y), f2bf(a1.z), f2bf(a1.w));
        *reinterpret_cast<ushort4*>(&sv[2][i][k0]) =
            make_ushort4(f2bf(a2.x), f2bf(a2.y), f2bf(a2.z), f2bf(a2.w));
        *reinterpret_cast<ushort4*>(&sv[3][i][k0]) =
            make_ushort4(f2bf(a3.x), f2bf(a3.y), f2bf(a3.z), f2bf(a3.w));
    }

    const float2 b0 = *reinterpret_cast<const float2*>(bias + 2 * l);
    float2 b1 = make_float2(0.f, 0.f);
    if (l < 16) b1 = *reinterpret_cast<const float2*>(bias + 128 + 2 * l);

    float lg[NOD];
#pragma unroll
    for (int od = 0; od < NOD; ++od) lg[od] = 0.f;
    const int iown = l & 31;

    __syncthreads();

    for (int it = 0; it < NROUT; ++it) {
        {
            float m = lg[0];
#pragma unroll
            for (int od = 1; od < NOD; ++od) m = fmaxf(m, lg[od]);
            float e[NOD];
            float s = 0.f;
#pragma unroll
            for (int od = 0; od < NOD; ++od) { e[od] = __expf(lg[od] - m); s += e[od]; }
            const float inv = 1.f / s;
            if (l < 32) {
#pragma unroll
                for (int od = 0; od < NOD; ++od)
                    srt_f[(w * NOD + od) * 33 + iown] = e[od] * inv;
            }
        }
        __builtin_amdgcn_wave_barrier();
        {
            const int od0 = l >> 3;
            float a0 = b0.x, a1 = b0.y;
#pragma unroll
            for (int i = 0; i < NI; ++i) {
                const unsigned d = *reinterpret_cast<const unsigned*>(&sv[w][i][2 * l]);
                const float r = srt_f[(w * NOD + od0) * 33 + i];
                a0 = fmaf(r, bf_lo(d), a0);
                a1 = fmaf(r, bf_hi(d), a1);
            }
            float ss = a0 * a0 + a1 * a1;
            ss += __shfl_xor(ss, 1, 8);
            ss += __shfl_xor(ss, 2, 8);
            ss += __shfl_xor(ss, 4, 8);
            const float sc = sqrtf(ss) / (1.f + ss);
            *reinterpret_cast<float2*>(&sact_f[w * 164 + 2 * l]) = make_float2(a0 * sc, a1 * sc);
            if (l < 16) {
                const int od1 = 8 + (l >> 3);
                float c0 = b1.x, c1 = b1.y;
#pragma unroll
                for (int i = 0; i < NI; ++i) {
                    const unsigned d = *reinterpret_cast<const unsigned*>(&sv[w][i][128 + 2 * l]);
                    const float r = srt_f[(w * NOD + od1) * 33 + i];
                    c0 = fmaf(r, bf_lo(d), c0);
                    c1 = fmaf(r, bf_hi(d), c1);
                }
                float s2 = c0 * c0 + c1 * c1;
                s2 += __shfl_xor(s2, 1, 8);
                s2 += __shfl_xor(s2, 2, 8);
                s2 += __shfl_xor(s2, 4, 8);
                const float sc2 = sqrtf(s2) / (1.f + s2);
                *reinterpret_cast<float2*>(&sact_f[w * 164 + 128 + 2 * l]) =
                    make_float2(c0 * sc2, c1 * sc2);
            }
        }
        __builtin_amdgcn_wave_barrier();
        if (it < NROUT - 1) {
#pragma unroll
            for (int r = 0; r < 5; ++r) {
                const int t  = l + 64 * r;
                const int i  = t & 31;
                const int od = t >> 5;
                const uint4 d0 = *reinterpret_cast<const uint4*>(&sv[w][i][od * NOA]);
                const uint4 d1 = *reinterpret_cast<const uint4*>(&sv[w][i][od * NOA + 8]);
                const float* ap = &sact_f[w * 164 + od * NOA];
                const float4 c0 = *reinterpret_cast<const float4*>(ap + 0);
                const float4 c1 = *reinterpret_cast<const float4*>(ap + 4);
                const float4 c2 = *reinterpret_cast<const float4*>(ap + 8);
                const float4 c3 = *reinterpret_cast<const float4*>(ap + 12);
                float acc;
                acc  = bf_lo(d0.x) * c0.x;
                acc = fmaf(bf_hi(d0.x), c0.y, acc);
                acc = fmaf(bf_lo(d0.y), c0.z, acc);
                acc = fmaf(bf_hi(d0.y), c0.w, acc);
                acc = fmaf(bf_lo(d0.z), c1.x, acc);
                acc = fmaf(bf_hi(d0.z), c1.y, acc);
                acc = fmaf(bf_lo(d0.w), c1.z, acc);
                acc = fmaf(bf_hi(d0.w), c1.w, acc);
                acc = fmaf(bf_lo(d1.x), c2.x, acc);
                acc = fmaf(bf_hi(d1.x), c2.y, acc);
                acc = fmaf(bf_lo(d1.y), c2.z, acc);
                acc = fmaf(bf_hi(d1.y), c2.w, acc);
                acc = fmaf(bf_lo(d1.z), c3.x, acc);
                acc = fmaf(bf_hi(d1.z), c3.y, acc);
                acc = fmaf(bf_lo(d1.w), c3.z, acc);
                acc = fmaf(bf_hi(d1.w), c3.w, acc);
                srt_f[(w * NOD + od) * 33 + i] = acc;
            }
            __builtin_amdgcn_wave_barrier();
#pragma unroll
            for (int od = 0; od < NOD; ++od)
                lg[od] += srt_f[(w * NOD + od) * 33 + iown];
            __builtin_amdgcn_wave_barrier();
        }
    }

    __syncthreads();
    if (tid < NK) {
        const float4 v = make_float4(sact_f[0 * 164 + tid], sact_f[1 * 164 + tid],
                                     sact_f[2 * 164 + tid], sact_f[3 * 164 + tid]);
        *reinterpret_cast<float4*>(out + ((size_t)b * NK + tid) * NHW + hw0) = v;
    }
}

extern "C" void kernel_launch(void* const* d_in, const int* in_sizes, int n_in,
                              void* d_out, int out_size, void* d_ws, size_t ws_size,
                              hipStream_t stream) {
    const float* x      = (const float*)d_in[0];
    const float* weight = (const float*)d_in[1];
    const float* bias   = (const float*)d_in[2];
    float* out          = (float*)d_out;

    if (ws_size >= WS_NEEDED) {
        unsigned short* w_bf = (unsigned short*)d_ws;
        float* x_t = (float*)((char*)d_ws + XT_OFF);
        prepass_kernel<<<320 + NB * 72, 256, 0, stream>>>(x, weight, w_bf, x_t);
        capsule_fused4_kernel<<<NROWS / 4, 512, 0, stream>>>(x_t, w_bf, bias, out);
    } else {
        capsule_fused_kernel<<<NROWS / 4, 256, 0, stream>>>(x, weight, bias, out);
    }
}

// Round 13
// 63.005 us; speedup vs baseline: 3.2915x; 3.2915x over previous
//
#include <hip/hip_runtime.h>
#include <math.h>

#define NB 32
#define NI 32
#define NA 16
#define NOD 10
#define NOA 16
#define NK 160         // NOD*NOA
#define NHW 144
#define NROUT 3
#define NROWS (NB*NHW) // 4608 pixel-rows
#define SVLD 168       // ushort row stride (336 B, 8B-aligned)

// workspace layout: [w_bf: 81920 ushort = 160KB][pad][x_t: NROWS*512 f32]
#define XT_OFF 262144
#define WS_NEEDED (XT_OFF + (size_t)NROWS * 512 * 4)

// ---- bf16 RNE pack / unpack ----
__device__ __forceinline__ unsigned short f2bf(float f) {
    unsigned b = __builtin_bit_cast(unsigned, f);
    b += 0x7fffu + ((b >> 16) & 1u);
    return (unsigned short)(b >> 16);
}
__device__ __forceinline__ float bf_lo(unsigned d) {
    return __builtin_bit_cast(float, d << 16);
}
__device__ __forceinline__ float bf_hi(unsigned d) {
    return __builtin_bit_cast(float, d & 0xffff0000u);
}

// =====================================================================
// Pre-pass (unchanged): weight f32->bf16; x -> per-block-contiguous
// x_t[b][hw/4][i][a][hw%4].
// =====================================================================
__global__ __launch_bounds__(256)
void prepass_kernel(const float* __restrict__ x,
                    const float* __restrict__ weight,
                    unsigned short* __restrict__ w_bf,
                    float* __restrict__ x_t)
{
    int bid = blockIdx.x;
    const int tid = threadIdx.x;
    if (bid < 320) {
        const int idx = bid * 256 + tid;
        w_bf[idx] = f2bf(weight[idx]);
        return;
    }
    bid -= 320;
    const int b  = bid / 72;
    const int r  = bid % 72;
    const int jt = r / 9;
    const int ht = r % 9;
    const int j0 = jt * 64, hw0 = ht * 16;

    __shared__ float tile[64][17];
    {
        const int hh = tid & 15;
        const int j1 = tid >> 4;
#pragma unroll
        for (int s = 0; s < 4; ++s) {
            const int jj = j1 + s * 16;
            tile[jj][hh] = x[(size_t)b * 73728 + (size_t)(j0 + jj) * NHW + hw0 + hh];
        }
    }
    __syncthreads();
    {
        const int jj = tid >> 2;
        const int p  = tid & 3;
#pragma unroll
        for (int s = 0; s < 4; ++s) {
            const int hwg = ht * 4 + s;
            x_t[((size_t)b * 36 + hwg) * 2048 + (size_t)(j0 + jj) * 4 + p] =
                tile[jj][s * 4 + p];
        }
    }
}

// =====================================================================
// Fused kernel v4.2: identical math to R12's v4.1 (both fixes kept).
// ONLY change: __launch_bounds__(512, 3). R12's (512,6) was read by
// hipcc as "min 6 BLOCKS/CU" (CUDA semantics) -> 48 waves/CU -> 40
// VGPR -> 700MB/dispatch scratch spill -> 207us. (512,3) = 3 blocks/CU
// = 24 waves/CU = 6 waves/SIMD, VGPR budget ~85 (kernel fits).
// =====================================================================
__global__ __launch_bounds__(512, 3)
void capsule_fused4_kernel(const float* __restrict__ x_t,           // [NROWS/4][2048]
                           const unsigned short* __restrict__ w_bf, // [NI*NA*NK]
                           const float* __restrict__ bias,          // [NK]
                           float* __restrict__ out)                 // [B,K,HW]
{
    __shared__ unsigned short sv[4][NI][SVLD];        // 43008 B bf16 votes
    __shared__ __align__(16) float smem[2696];        // 10784 B routing bufs
    float* const slog_f         = smem;                               // [4][10][34] f32
    unsigned short* const srt_h = (unsigned short*)(smem + 1360);     // [4][10][34] bf16
    float* const sact_f         = smem + 2040;                        // [4][164] f32
    float* const xp             = smem;               // x staging (phase 1 only)

    const int tid = threadIdx.x;
    const int wid = tid >> 6;
    const int l   = tid & 63;
    const int w2  = wid >> 1;          // local row 0..3
    const int hf  = wid & 1;           // od/k half
    const int b   = blockIdx.x / (NHW / 4);
    const int hw0 = (blockIdx.x % (NHW / 4)) * 4;

    // ---- phase 1a: contiguous x slice -> xp ([i][a][p] layout) ----
    {
        const float4* src = reinterpret_cast<const float4*>(x_t + (size_t)blockIdx.x * 2048);
        reinterpret_cast<float4*>(xp)[tid] = src[tid];
    }
    __syncthreads();

    // ---- phase 1b: votes. task (i, k-oct): 640 tasks over 512 thr ----
    for (int t = tid; t < NI * 20; t += 512) {
        const int i  = t / 20;
        const int ko = t - i * 20;
        const int k0 = ko * 8;
        const uint4* wp = reinterpret_cast<const uint4*>(w_bf + (size_t)i * NA * NK + k0);
        float4 acc[4][2];
#pragma unroll
        for (int p = 0; p < 4; ++p) {
            acc[p][0] = make_float4(0.f, 0.f, 0.f, 0.f);
            acc[p][1] = make_float4(0.f, 0.f, 0.f, 0.f);
        }
#pragma unroll
        for (int a = 0; a < NA; ++a) {
            const uint4 wv = wp[(size_t)a * 20];
            const float w0 = bf_lo(wv.x), w1 = bf_hi(wv.x);
            const float w2_ = bf_lo(wv.y), w3 = bf_hi(wv.y);
            const float w4 = bf_lo(wv.z), w5 = bf_hi(wv.z);
            const float w6 = bf_lo(wv.w), w7 = bf_hi(wv.w);
            const float4 xa = *reinterpret_cast<const float4*>(&xp[(i * NA + a) * 4]);
            const float xs[4] = {xa.x, xa.y, xa.z, xa.w};
#pragma unroll
            for (int p = 0; p < 4; ++p) {
                const float xv = xs[p];
                acc[p][0].x = fmaf(xv, w0, acc[p][0].x);
                acc[p][0].y = fmaf(xv, w1, acc[p][0].y);
                acc[p][0].z = fmaf(xv, w2_, acc[p][0].z);
                acc[p][0].w = fmaf(xv, w3, acc[p][0].w);
                acc[p][1].x = fmaf(xv, w4, acc[p][1].x);
                acc[p][1].y = fmaf(xv, w5, acc[p][1].y);
                acc[p][1].z = fmaf(xv, w6, acc[p][1].z);
                acc[p][1].w = fmaf(xv, w7, acc[p][1].w);
            }
        }
#pragma unroll
        for (int p = 0; p < 4; ++p) {
            *reinterpret_cast<ushort4*>(&sv[p][i][k0]) =
                make_ushort4(f2bf(acc[p][0].x), f2bf(acc[p][0].y),
                             f2bf(acc[p][0].z), f2bf(acc[p][0].w));
            *reinterpret_cast<ushort4*>(&sv[p][i][k0 + 4]) =
                make_ushort4(f2bf(acc[p][1].x), f2bf(acc[p][1].y),
                             f2bf(acc[p][1].z), f2bf(acc[p][1].w));
        }
    }

    // ---- per-lane routing constants ----
    const int kb = hf * 80;            // k-base of this wave's half
    const int ob = hf * 5;             // od-base
    int kq = 0, hh = 0, odg = 0, kg = 0;
    float4 bq = make_float4(0.f, 0.f, 0.f, 0.f);
    if (l < 40) {                      // preact lane map: (k-quad, i-half)
        kq  = l >> 1;                  // 0..19 (k-quad within half)
        hh  = l & 1;                   // i-half
        odg = ob + (kq >> 2);          // global od of this k-quad
        kg  = kb + kq * 4;             // global k
        if (hh == 0)                   // bias on ONE lane of the pair
            bq = *reinterpret_cast<const float4*>(bias + kg);
    }
    const int li = l & 31;

    float lgp[3] = {0.f, 0.f, 0.f};    // logits owned as (odl*32+i) tasks

    __syncthreads();                    // sv complete; xp dead

    for (int it = 0; it < NROUT; ++it) {
        // ---- softmax over all 10 od (iter >= 1; iter0 route = 0.1) ----
        if (it > 0) {
            float e[NOD];
            float m = -1e30f;
#pragma unroll
            for (int od = 0; od < NOD; ++od) {
                e[od] = slog_f[(w2 * NOD + od) * 34 + li];
                m = fmaxf(m, e[od]);
            }
            float s = 0.f;
#pragma unroll
            for (int od = 0; od < NOD; ++od) {
                e[od] = __expf(e[od] - m);
                s += e[od];
            }
            const float inv = 1.f / s;
            if (l < 32) {
#pragma unroll
                for (int odl = 0; odl < 5; ++odl)
                    srt_h[(w2 * NOD + ob + odl) * 34 + li] = f2bf(e[ob + odl] * inv);
            }
            __syncthreads();   // all slog reads done before agreement rewrites
        }

        // ---- preact + squash: lane = (k-quad, i-half) ----
        if (l < 40) {
            float a0 = bq.x, a1 = bq.y, a2 = bq.z, a3 = bq.w;
            const unsigned short* svb  = &sv[w2][hh * 16][kg];
            const unsigned short* srow = &srt_h[(w2 * NOD + odg) * 34 + hh * 16];
#pragma unroll
            for (int s2 = 0; s2 < 8; ++s2) {
                float r0, r1;
                if (it == 0) {
                    r0 = 0.1f; r1 = 0.1f;
                } else {
                    const unsigned u = *reinterpret_cast<const unsigned*>(srow + 2 * s2);
                    r0 = bf_lo(u); r1 = bf_hi(u);
                }
                const uint2 d0 = *reinterpret_cast<const uint2*>(svb + (2 * s2) * SVLD);
                const uint2 d1 = *reinterpret_cast<const uint2*>(svb + (2 * s2 + 1) * SVLD);
                a0 = fmaf(r0, bf_lo(d0.x), a0);
                a1 = fmaf(r0, bf_hi(d0.x), a1);
                a2 = fmaf(r0, bf_lo(d0.y), a2);
                a3 = fmaf(r0, bf_hi(d0.y), a3);
                a0 = fmaf(r1, bf_lo(d1.x), a0);
                a1 = fmaf(r1, bf_hi(d1.x), a1);
                a2 = fmaf(r1, bf_lo(d1.y), a2);
                a3 = fmaf(r1, bf_hi(d1.y), a3);
            }
            // combine i-halves (lane pairs 2kq | 2kq+1)
            a0 += __shfl_xor(a0, 1, 2);
            a1 += __shfl_xor(a1, 1, 2);
            a2 += __shfl_xor(a2, 1, 2);
            a3 += __shfl_xor(a3, 1, 2);
            // squash over the od's 16 k (4 quads = 8-lane group)
            float ss = a0 * a0 + a1 * a1 + a2 * a2 + a3 * a3;
            ss += __shfl_xor(ss, 2, 8);
            ss += __shfl_xor(ss, 4, 8);
            const float sc = sqrtf(ss) / (1.f + ss);
            if (hh == 0)
                *reinterpret_cast<float4*>(&sact_f[w2 * 164 + kg]) =
                    make_float4(a0 * sc, a1 * sc, a2 * sc, a3 * sc);
        }
        __builtin_amdgcn_wave_barrier();

        if (it < NROUT - 1) {
            // ---- agreement: tasks t = odl*32 + i (own od-half) ----
#pragma unroll
            for (int r = 0; r < 3; ++r) {
                const int t = l + 64 * r;
                if (t < 160) {
                    const int odl = t >> 5;
                    const int i   = t & 31;
                    const int od  = ob + odl;
                    const int kk  = od * 16;
                    const uint4 d0 = *reinterpret_cast<const uint4*>(&sv[w2][i][kk]);
                    const uint4 d1 = *reinterpret_cast<const uint4*>(&sv[w2][i][kk + 8]);
                    const float* ap = &sact_f[w2 * 164 + kk];
                    const float4 c0 = *reinterpret_cast<const float4*>(ap + 0);
                    const float4 c1 = *reinterpret_cast<const float4*>(ap + 4);
                    const float4 c2 = *reinterpret_cast<const float4*>(ap + 8);
                    const float4 c3 = *reinterpret_cast<const float4*>(ap + 12);
                    float acc;
                    acc  = bf_lo(d0.x) * c0.x;
                    acc = fmaf(bf_hi(d0.x), c0.y, acc);
                    acc = fmaf(bf_lo(d0.y), c0.z, acc);
                    acc = fmaf(bf_hi(d0.y), c0.w, acc);
                    acc = fmaf(bf_lo(d0.z), c1.x, acc);
                    acc = fmaf(bf_hi(d0.z), c1.y, acc);
                    acc = fmaf(bf_lo(d0.w), c1.z, acc);
                    acc = fmaf(bf_hi(d0.w), c1.w, acc);
                    acc = fmaf(bf_lo(d1.x), c2.x, acc);
                    acc = fmaf(bf_hi(d1.x), c2.y, acc);
                    acc = fmaf(bf_lo(d1.y), c2.z, acc);
                    acc = fmaf(bf_hi(d1.y), c2.w, acc);
                    acc = fmaf(bf_lo(d1.z), c3.x, acc);
                    acc = fmaf(bf_hi(d1.z), c3.y, acc);
                    acc = fmaf(bf_lo(d1.w), c3.z, acc);
                    acc = fmaf(bf_hi(d1.w), c3.w, acc);
                    lgp[r] += acc;
                    slog_f[(w2 * NOD + od) * 34 + i] = lgp[r];
                }
            }
            __syncthreads();   // logits visible to the sibling half-wave
        }
    }

    // ---- output: float4 across the block's 4 consecutive pixels ----
    __syncthreads();
    if (tid < NK) {
        const float4 v = make_float4(sact_f[0 * 164 + tid], sact_f[1 * 164 + tid],
                                     sact_f[2 * 164 + tid], sact_f[3 * 164 + tid]);
        *reinterpret_cast<float4*>(out + ((size_t)b * NK + tid) * NHW + hw0) = v;
    }
}

// =====================================================================
// Fallback (R8 fused, f32 weight, direct x read) if ws too small.
// =====================================================================
__global__ __launch_bounds__(256)
void capsule_fused_kernel(const float* __restrict__ x,
                          const float* __restrict__ weight,
                          const float* __restrict__ bias,
                          float* __restrict__ out)
{
    __shared__ unsigned short sv[4][NI][SVLD];
    __shared__ __align__(16) float pool[2048];
    float* const srt_f  = pool;
    float* const sact_f = pool + 4 * NOD * 33;

    const int tid = threadIdx.x;
    const int w   = tid >> 6;
    const int l   = tid & 63;
    const int b   = blockIdx.x / (NHW / 4);
    const int hw0 = (blockIdx.x % (NHW / 4)) * 4;

    {
        const float* xb = x + ((size_t)b * NI * NA) * NHW + hw0;
        for (int j = tid; j < NI * NA; j += 256) {
            const float4 v = *reinterpret_cast<const float4*>(xb + (size_t)j * NHW);
            *reinterpret_cast<float4*>(&pool[j * 4]) = v;
        }
    }
    __syncthreads();

    for (int j = tid; j < NI * 40; j += 256) {
        const int i  = j / 40;
        const int kq = j - i * 40;
        const int k0 = kq * 4;
        const float4* wp = reinterpret_cast<const float4*>(weight + (size_t)i * NA * NK + k0);
        float4 a0 = make_float4(0.f,0.f,0.f,0.f), a1 = a0, a2 = a0, a3 = a0;
#pragma unroll
        for (int a = 0; a < NA; ++a) {
            const float4 w4 = wp[(size_t)a * 40];
            const float4 xa = *reinterpret_cast<const float4*>(&pool[(i * NA + a) * 4]);
            a0.x = fmaf(xa.x, w4.x, a0.x); a0.y = fmaf(xa.x, w4.y, a0.y);
            a0.z = fmaf(xa.x, w4.z, a0.z); a0.w = fmaf(xa.x, w4.w, a0.w);
            a1.x = fmaf(xa.y, w4.x, a1.x); a1.y = fmaf(xa.y, w4.y, a1.y);
            a1.z = fmaf(xa.y, w4.z, a1.z); a1.w = fmaf(xa.y, w4.w, a1.w);
            a2.x = fmaf(xa.z, w4.x, a2.x); a2.y = fmaf(xa.z, w4.y, a2.y);
            a2.z = fmaf(xa.z, w4.z, a2.z); a2.w = fmaf(xa.z, w4.w, a2.w);
            a3.x = fmaf(xa.w, w4.x, a3.x); a3.y = fmaf(xa.w, w4.y, a3.y);
            a3.z = fmaf(xa.w, w4.z, a3.z); a3.w = fmaf(xa.w, w4.w, a3.w);
        }
        *reinterpret_cast<ushort4*>(&sv[0][i][k0]) =
            make_ushort4(f2bf(a0.x), f2bf(a0.y), f2bf(a0.z), f2bf(a0.w));
        *reinterpret_cast<ushort4*>(&sv[1][i][k0]) =
            make_ushort4(f2bf(a1.x), f2bf(a1.y), f2bf(a1.z), f2bf(a1.w));
        *reinterpret_cast<ushort4*>(&sv[2][i][k0]) =
            make_ushort4(f2bf(a2.x), f2bf(a2.y), f2bf(a2.z), f2bf(a2.w));
        *reinterpret_cast<ushort4*>(&sv[3][i][k0]) =
            make_ushort4(f2bf(a3.x), f2bf(a3.y), f2bf(a3.z), f2bf(a3.w));
    }

    const float2 b0 = *reinterpret_cast<const float2*>(bias + 2 * l);
    float2 b1 = make_float2(0.f, 0.f);
    if (l < 16) b1 = *reinterpret_cast<const float2*>(bias + 128 + 2 * l);

    float lg[NOD];
#pragma unroll
    for (int od = 0; od < NOD; ++od) lg[od] = 0.f;
    const int iown = l & 31;

    __syncthreads();

    for (int it = 0; it < NROUT; ++it) {
        {
            float m = lg[0];
#pragma unroll
            for (int od = 1; od < NOD; ++od) m = fmaxf(m, lg[od]);
            float e[NOD];
            float s = 0.f;
#pragma unroll
            for (int od = 0; od < NOD; ++od) { e[od] = __expf(lg[od] - m); s += e[od]; }
            const float inv = 1.f / s;
            if (l < 32) {
#pragma unroll
                for (int od = 0; od < NOD; ++od)
                    srt_f[(w * NOD + od) * 33 + iown] = e[od] * inv;
            }
        }
        __builtin_amdgcn_wave_barrier();
        {
            const int od0 = l >> 3;
            float a0 = b0.x, a1 = b0.y;
#pragma unroll
            for (int i = 0; i < NI; ++i) {
                const unsigned d = *reinterpret_cast<const unsigned*>(&sv[w][i][2 * l]);
                const float r = srt_f[(w * NOD + od0) * 33 + i];
                a0 = fmaf(r, bf_lo(d), a0);
                a1 = fmaf(r, bf_hi(d), a1);
            }
            float ss = a0 * a0 + a1 * a1;
            ss += __shfl_xor(ss, 1, 8);
            ss += __shfl_xor(ss, 2, 8);
            ss += __shfl_xor(ss, 4, 8);
            const float sc = sqrtf(ss) / (1.f + ss);
            *reinterpret_cast<float2*>(&sact_f[w * 164 + 2 * l]) = make_float2(a0 * sc, a1 * sc);
            if (l < 16) {
                const int od1 = 8 + (l >> 3);
                float c0 = b1.x, c1 = b1.y;
#pragma unroll
                for (int i = 0; i < NI; ++i) {
                    const unsigned d = *reinterpret_cast<const unsigned*>(&sv[w][i][128 + 2 * l]);
                    const float r = srt_f[(w * NOD + od1) * 33 + i];
                    c0 = fmaf(r, bf_lo(d), c0);
                    c1 = fmaf(r, bf_hi(d), c1);
                }
                float s2 = c0 * c0 + c1 * c1;
                s2 += __shfl_xor(s2, 1, 8);
                s2 += __shfl_xor(s2, 2, 8);
                s2 += __shfl_xor(s2, 4, 8);
                const float sc2 = sqrtf(s2) / (1.f + s2);
                *reinterpret_cast<float2*>(&sact_f[w * 164 + 128 + 2 * l]) =
                    make_float2(c0 * sc2, c1 * sc2);
            }
        }
        __builtin_amdgcn_wave_barrier();
        if (it < NROUT - 1) {
#pragma unroll
            for (int r = 0; r < 5; ++r) {
                const int t  = l + 64 * r;
                const int i  = t & 31;
                const int od = t >> 5;
                const uint4 d0 = *reinterpret_cast<const uint4*>(&sv[w][i][od * NOA]);
                const uint4 d1 = *reinterpret_cast<const uint4*>(&sv[w][i][od * NOA + 8]);
                const float* ap = &sact_f[w * 164 + od * NOA];
                const float4 c0 = *reinterpret_cast<const float4*>(ap + 0);
                const float4 c1 = *reinterpret_cast<const float4*>(ap + 4);
                const float4 c2 = *reinterpret_cast<const float4*>(ap + 8);
                const float4 c3 = *reinterpret_cast<const float4*>(ap + 12);
                float acc;
                acc  = bf_lo(d0.x) * c0.x;
                acc = fmaf(bf_hi(d0.x), c0.y, acc);
                acc = fmaf(bf_lo(d0.y), c0.z, acc);
                acc = fmaf(bf_hi(d0.y), c0.w, acc);
                acc = fmaf(bf_lo(d0.z), c1.x, acc);
                acc = fmaf(bf_hi(d0.z), c1.y, acc);
                acc = fmaf(bf_lo(d0.w), c1.z, acc);
                acc = fmaf(bf_hi(d0.w), c1.w, acc);
                acc = fmaf(bf_lo(d1.x), c2.x, acc);
                acc = fmaf(bf_hi(d1.x), c2.y, acc);
                acc = fmaf(bf_lo(d1.y), c2.z, acc);
                acc = fmaf(bf_hi(d1.y), c2.w, acc);
                acc = fmaf(bf_lo(d1.z), c3.x, acc);
                acc = fmaf(bf_hi(d1.z), c3.y, acc);
                acc = fmaf(bf_lo(d1.w), c3.z, acc);
                acc = fmaf(bf_hi(d1.w), c3.w, acc);
                srt_f[(w * NOD + od) * 33 + i] = acc;
            }
            __builtin_amdgcn_wave_barrier();
#pragma unroll
            for (int od = 0; od < NOD; ++od)
                lg[od] += srt_f[(w * NOD + od) * 33 + iown];
            __builtin_amdgcn_wave_barrier();
        }
    }

    __syncthreads();
    if (tid < NK) {
        const float4 v = make_float4(sact_f[0 * 164 + tid], sact_f[1 * 164 + tid],
                                     sact_f[2 * 164 + tid], sact_f[3 * 164 + tid]);
        *reinterpret_cast<float4*>(out + ((size_t)b * NK + tid) * NHW + hw0) = v;
    }
}

extern "C" void kernel_launch(void* const* d_in, const int* in_sizes, int n_in,
                              void* d_out, int out_size, void* d_ws, size_t ws_size,
                              hipStream_t stream) {
    const float* x      = (const float*)d_in[0];
    const float* weight = (const float*)d_in[1];
    const float* bias   = (const float*)d_in[2];
    float* out          = (float*)d_out;

    if (ws_size >= WS_NEEDED) {
        unsigned short* w_bf = (unsigned short*)d_ws;
        float* x_t = (float*)((char*)d_ws + XT_OFF);
        prepass_kernel<<<320 + NB * 72, 256, 0, stream>>>(x, weight, w_bf, x_t);
        capsule_fused4_kernel<<<NROWS / 4, 512, 0, stream>>>(x_t, w_bf, bias, out);
    } else {
        capsule_fused_kernel<<<NROWS / 4, 256, 0, stream>>>(x, weight, bias, out);
    }
}

// Round 14
// 48.972 us; speedup vs baseline: 4.2347x; 1.2865x over previous
//
#include <hip/hip_runtime.h>
#include <math.h>

#define NB 32
#define NI 32
#define NA 16
#define NOD 10
#define NOA 16
#define NK 160         // NOD*NOA
#define NHW 144
#define NROUT 3
#define NROWS (NB*NHW) // 4608 pixel-rows
#define SVLD 168       // ushort row stride (336 B, 8B-aligned)

// workspace layout: [w_bf: 81920 ushort = 160KB][pad][x_t: NROWS*512 f32]
#define XT_OFF 262144
#define WS_NEEDED (XT_OFF + (size_t)NROWS * 512 * 4)

// ---- bf16 RNE pack / unpack ----
__device__ __forceinline__ unsigned short f2bf(float f) {
    unsigned b = __builtin_bit_cast(unsigned, f);
    b += 0x7fffu + ((b >> 16) & 1u);
    return (unsigned short)(b >> 16);
}
__device__ __forceinline__ float bf_lo(unsigned d) {
    return __builtin_bit_cast(float, d << 16);
}
__device__ __forceinline__ float bf_hi(unsigned d) {
    return __builtin_bit_cast(float, d & 0xffff0000u);
}

// =====================================================================
// Pre-pass (unchanged): weight f32->bf16; x -> per-block-contiguous
// x_t[b][hw/4][i][a][hw%4].
// =====================================================================
__global__ __launch_bounds__(256)
void prepass_kernel(const float* __restrict__ x,
                    const float* __restrict__ weight,
                    unsigned short* __restrict__ w_bf,
                    float* __restrict__ x_t)
{
    int bid = blockIdx.x;
    const int tid = threadIdx.x;
    if (bid < 320) {
        const int idx = bid * 256 + tid;
        w_bf[idx] = f2bf(weight[idx]);
        return;
    }
    bid -= 320;
    const int b  = bid / 72;
    const int r  = bid % 72;
    const int jt = r / 9;
    const int ht = r % 9;
    const int j0 = jt * 64, hw0 = ht * 16;

    __shared__ float tile[64][17];
    {
        const int hh = tid & 15;
        const int j1 = tid >> 4;
#pragma unroll
        for (int s = 0; s < 4; ++s) {
            const int jj = j1 + s * 16;
            tile[jj][hh] = x[(size_t)b * 73728 + (size_t)(j0 + jj) * NHW + hw0 + hh];
        }
    }
    __syncthreads();
    {
        const int jj = tid >> 2;
        const int p  = tid & 3;
#pragma unroll
        for (int s = 0; s < 4; ++s) {
            const int hwg = ht * 4 + s;
            x_t[((size_t)b * 36 + hwg) * 2048 + (size_t)(j0 + jj) * 4 + p] =
                tile[jj][s * 4 + p];
        }
    }
}

// =====================================================================
// Fused kernel v5: R13's correct v4.2 routing, but votes task shrunk
// to (i, k-QUAD) so acc = 16 VGPR (was 32), and __launch_bounds__(512,4)
// -> 64-VGPR budget. VGPR occupancy quantum on gfx950 steps at
// {64,128,256} -> {32,16,8} waves/CU; R13's 84 VGPR rounded to 128 ->
// 16 waves/CU (od-split wasted). At <=64 VGPR, LDS (54.3KB, 3 blocks)
// caps us at 24 waves/CU = 1.5x R13.
// =====================================================================
__global__ __launch_bounds__(512, 4)
void capsule_fused5_kernel(const float* __restrict__ x_t,           // [NROWS/4][2048]
                           const unsigned short* __restrict__ w_bf, // [NI*NA*NK]
                           const float* __restrict__ bias,          // [NK]
                           float* __restrict__ out)                 // [B,K,HW]
{
    __shared__ unsigned short sv[4][NI][SVLD];        // 43008 B bf16 votes
    __shared__ __align__(16) float smem[2696];        // 10784 B routing bufs
    float* const slog_f         = smem;                               // [4][10][34] f32
    unsigned short* const srt_h = (unsigned short*)(smem + 1360);     // [4][10][34] bf16
    float* const sact_f         = smem + 2040;                        // [4][164] f32
    float* const xp             = smem;               // x staging (phase 1 only)

    const int tid = threadIdx.x;
    const int wid = tid >> 6;
    const int l   = tid & 63;
    const int w2  = wid >> 1;          // local row 0..3
    const int hf  = wid & 1;           // od/k half
    const int b   = blockIdx.x / (NHW / 4);
    const int hw0 = (blockIdx.x % (NHW / 4)) * 4;

    // ---- phase 1a: contiguous x slice -> xp ([i][a][p] layout) ----
    {
        const float4* src = reinterpret_cast<const float4*>(x_t + (size_t)blockIdx.x * 2048);
        reinterpret_cast<float4*>(xp)[tid] = src[tid];
    }
    __syncthreads();

    // ---- phase 1b: votes. task (i, k-QUAD): 1280 tasks, 16-reg acc ----
    for (int t = tid; t < NI * 40; t += 512) {
        const int i  = t / 40;
        const int kq = t - i * 40;
        const int k0 = kq * 4;
        const unsigned short* wp = w_bf + (size_t)i * NA * NK + k0;
        float4 a0 = make_float4(0.f, 0.f, 0.f, 0.f);   // row 0, k0..k0+3
        float4 a1 = a0, a2 = a0, a3 = a0;              // rows 1..3
#pragma unroll
        for (int a = 0; a < NA; ++a) {
            const uint2 wv = *reinterpret_cast<const uint2*>(wp + (size_t)a * NK);
            const float w0 = bf_lo(wv.x), w1 = bf_hi(wv.x);
            const float w2_ = bf_lo(wv.y), w3 = bf_hi(wv.y);
            const float4 xa = *reinterpret_cast<const float4*>(&xp[(i * NA + a) * 4]);
            a0.x = fmaf(xa.x, w0, a0.x); a0.y = fmaf(xa.x, w1, a0.y);
            a0.z = fmaf(xa.x, w2_, a0.z); a0.w = fmaf(xa.x, w3, a0.w);
            a1.x = fmaf(xa.y, w0, a1.x); a1.y = fmaf(xa.y, w1, a1.y);
            a1.z = fmaf(xa.y, w2_, a1.z); a1.w = fmaf(xa.y, w3, a1.w);
            a2.x = fmaf(xa.z, w0, a2.x); a2.y = fmaf(xa.z, w1, a2.y);
            a2.z = fmaf(xa.z, w2_, a2.z); a2.w = fmaf(xa.z, w3, a2.w);
            a3.x = fmaf(xa.w, w0, a3.x); a3.y = fmaf(xa.w, w1, a3.y);
            a3.z = fmaf(xa.w, w2_, a3.z); a3.w = fmaf(xa.w, w3, a3.w);
        }
        *reinterpret_cast<ushort4*>(&sv[0][i][k0]) =
            make_ushort4(f2bf(a0.x), f2bf(a0.y), f2bf(a0.z), f2bf(a0.w));
        *reinterpret_cast<ushort4*>(&sv[1][i][k0]) =
            make_ushort4(f2bf(a1.x), f2bf(a1.y), f2bf(a1.z), f2bf(a1.w));
        *reinterpret_cast<ushort4*>(&sv[2][i][k0]) =
            make_ushort4(f2bf(a2.x), f2bf(a2.y), f2bf(a2.z), f2bf(a2.w));
        *reinterpret_cast<ushort4*>(&sv[3][i][k0]) =
            make_ushort4(f2bf(a3.x), f2bf(a3.y), f2bf(a3.z), f2bf(a3.w));
    }

    // ---- per-lane routing constants ----
    const int kb = hf * 80;            // k-base of this wave's half
    const int ob = hf * 5;             // od-base
    int kq = 0, hh = 0, odg = 0, kg = 0;
    float4 bq = make_float4(0.f, 0.f, 0.f, 0.f);
    if (l < 40) {                      // preact lane map: (k-quad, i-half)
        kq  = l >> 1;                  // 0..19 (k-quad within half)
        hh  = l & 1;                   // i-half
        odg = ob + (kq >> 2);          // global od of this k-quad
        kg  = kb + kq * 4;             // global k
        if (hh == 0)                   // bias on ONE lane of the pair
            bq = *reinterpret_cast<const float4*>(bias + kg);
    }
    const int li = l & 31;

    float lgp[3] = {0.f, 0.f, 0.f};    // logits owned as (odl*32+i) tasks

    __syncthreads();                    // sv complete; xp dead

    for (int it = 0; it < NROUT; ++it) {
        // ---- softmax over all 10 od (iter >= 1; iter0 route = 0.1) ----
        if (it > 0) {
            float e[NOD];
            float m = -1e30f;
#pragma unroll
            for (int od = 0; od < NOD; ++od) {
                e[od] = slog_f[(w2 * NOD + od) * 34 + li];
                m = fmaxf(m, e[od]);
            }
            float s = 0.f;
#pragma unroll
            for (int od = 0; od < NOD; ++od) {
                e[od] = __expf(e[od] - m);
                s += e[od];
            }
            const float inv = 1.f / s;
            if (l < 32) {
#pragma unroll
                for (int odl = 0; odl < 5; ++odl)
                    srt_h[(w2 * NOD + ob + odl) * 34 + li] = f2bf(e[ob + odl] * inv);
            }
            __syncthreads();   // all slog reads done before agreement rewrites
        }

        // ---- preact + squash: lane = (k-quad, i-half) ----
        if (l < 40) {
            float a0 = bq.x, a1 = bq.y, a2 = bq.z, a3 = bq.w;
            const unsigned short* svb  = &sv[w2][hh * 16][kg];
            const unsigned short* srow = &srt_h[(w2 * NOD + odg) * 34 + hh * 16];
#pragma unroll
            for (int s2 = 0; s2 < 8; ++s2) {
                float r0, r1;
                if (it == 0) {
                    r0 = 0.1f; r1 = 0.1f;
                } else {
                    const unsigned u = *reinterpret_cast<const unsigned*>(srow + 2 * s2);
                    r0 = bf_lo(u); r1 = bf_hi(u);
                }
                const uint2 d0 = *reinterpret_cast<const uint2*>(svb + (2 * s2) * SVLD);
                const uint2 d1 = *reinterpret_cast<const uint2*>(svb + (2 * s2 + 1) * SVLD);
                a0 = fmaf(r0, bf_lo(d0.x), a0);
                a1 = fmaf(r0, bf_hi(d0.x), a1);
                a2 = fmaf(r0, bf_lo(d0.y), a2);
                a3 = fmaf(r0, bf_hi(d0.y), a3);
                a0 = fmaf(r1, bf_lo(d1.x), a0);
                a1 = fmaf(r1, bf_hi(d1.x), a1);
                a2 = fmaf(r1, bf_lo(d1.y), a2);
                a3 = fmaf(r1, bf_hi(d1.y), a3);
            }
            // combine i-halves (lane pairs 2kq | 2kq+1)
            a0 += __shfl_xor(a0, 1, 2);
            a1 += __shfl_xor(a1, 1, 2);
            a2 += __shfl_xor(a2, 1, 2);
            a3 += __shfl_xor(a3, 1, 2);
            // squash over the od's 16 k (4 quads = 8-lane group)
            float ss = a0 * a0 + a1 * a1 + a2 * a2 + a3 * a3;
            ss += __shfl_xor(ss, 2, 8);
            ss += __shfl_xor(ss, 4, 8);
            const float sc = sqrtf(ss) / (1.f + ss);
            if (hh == 0)
                *reinterpret_cast<float4*>(&sact_f[w2 * 164 + kg]) =
                    make_float4(a0 * sc, a1 * sc, a2 * sc, a3 * sc);
        }
        __builtin_amdgcn_wave_barrier();

        if (it < NROUT - 1) {
            // ---- agreement: tasks t = odl*32 + i (own od-half) ----
#pragma unroll
            for (int r = 0; r < 3; ++r) {
                const int t = l + 64 * r;
                if (t < 160) {
                    const int odl = t >> 5;
                    const int i   = t & 31;
                    const int od  = ob + odl;
                    const int kk  = od * 16;
                    const uint4 d0 = *reinterpret_cast<const uint4*>(&sv[w2][i][kk]);
                    const uint4 d1 = *reinterpret_cast<const uint4*>(&sv[w2][i][kk + 8]);
                    const float* ap = &sact_f[w2 * 164 + kk];
                    const float4 c0 = *reinterpret_cast<const float4*>(ap + 0);
                    const float4 c1 = *reinterpret_cast<const float4*>(ap + 4);
                    const float4 c2 = *reinterpret_cast<const float4*>(ap + 8);
                    const float4 c3 = *reinterpret_cast<const float4*>(ap + 12);
                    float acc;
                    acc  = bf_lo(d0.x) * c0.x;
                    acc = fmaf(bf_hi(d0.x), c0.y, acc);
                    acc = fmaf(bf_lo(d0.y), c0.z, acc);
                    acc = fmaf(bf_hi(d0.y), c0.w, acc);
                    acc = fmaf(bf_lo(d0.z), c1.x, acc);
                    acc = fmaf(bf_hi(d0.z), c1.y, acc);
                    acc = fmaf(bf_lo(d0.w), c1.z, acc);
                    acc = fmaf(bf_hi(d0.w), c1.w, acc);
                    acc = fmaf(bf_lo(d1.x), c2.x, acc);
                    acc = fmaf(bf_hi(d1.x), c2.y, acc);
                    acc = fmaf(bf_lo(d1.y), c2.z, acc);
                    acc = fmaf(bf_hi(d1.y), c2.w, acc);
                    acc = fmaf(bf_lo(d1.z), c3.x, acc);
                    acc = fmaf(bf_hi(d1.z), c3.y, acc);
                    acc = fmaf(bf_lo(d1.w), c3.z, acc);
                    acc = fmaf(bf_hi(d1.w), c3.w, acc);
                    lgp[r] += acc;
                    slog_f[(w2 * NOD + od) * 34 + i] = lgp[r];
                }
            }
            __syncthreads();   // logits visible to the sibling half-wave
        }
    }

    // ---- output: float4 across the block's 4 consecutive pixels ----
    __syncthreads();
    if (tid < NK) {
        const float4 v = make_float4(sact_f[0 * 164 + tid], sact_f[1 * 164 + tid],
                                     sact_f[2 * 164 + tid], sact_f[3 * 164 + tid]);
        *reinterpret_cast<float4*>(out + ((size_t)b * NK + tid) * NHW + hw0) = v;
    }
}

// =====================================================================
// Fallback (R8 fused, f32 weight, direct x read) if ws too small.
// =====================================================================
__global__ __launch_bounds__(256)
void capsule_fused_kernel(const float* __restrict__ x,
                          const float* __restrict__ weight,
                          const float* __restrict__ bias,
                          float* __restrict__ out)
{
    __shared__ unsigned short sv[4][NI][SVLD];
    __shared__ __align__(16) float pool[2048];
    float* const srt_f  = pool;
    float* const sact_f = pool + 4 * NOD * 33;

    const int tid = threadIdx.x;
    const int w   = tid >> 6;
    const int l   = tid & 63;
    const int b   = blockIdx.x / (NHW / 4);
    const int hw0 = (blockIdx.x % (NHW / 4)) * 4;

    {
        const float* xb = x + ((size_t)b * NI * NA) * NHW + hw0;
        for (int j = tid; j < NI * NA; j += 256) {
            const float4 v = *reinterpret_cast<const float4*>(xb + (size_t)j * NHW);
            *reinterpret_cast<float4*>(&pool[j * 4]) = v;
        }
    }
    __syncthreads();

    for (int j = tid; j < NI * 40; j += 256) {
        const int i  = j / 40;
        const int kq = j - i * 40;
        const int k0 = kq * 4;
        const float4* wp = reinterpret_cast<const float4*>(weight + (size_t)i * NA * NK + k0);
        float4 a0 = make_float4(0.f,0.f,0.f,0.f), a1 = a0, a2 = a0, a3 = a0;
#pragma unroll
        for (int a = 0; a < NA; ++a) {
            const float4 w4 = wp[(size_t)a * 40];
            const float4 xa = *reinterpret_cast<const float4*>(&pool[(i * NA + a) * 4]);
            a0.x = fmaf(xa.x, w4.x, a0.x); a0.y = fmaf(xa.x, w4.y, a0.y);
            a0.z = fmaf(xa.x, w4.z, a0.z); a0.w = fmaf(xa.x, w4.w, a0.w);
            a1.x = fmaf(xa.y, w4.x, a1.x); a1.y = fmaf(xa.y, w4.y, a1.y);
            a1.z = fmaf(xa.y, w4.z, a1.z); a1.w = fmaf(xa.y, w4.w, a1.w);
            a2.x = fmaf(xa.z, w4.x, a2.x); a2.y = fmaf(xa.z, w4.y, a2.y);
            a2.z = fmaf(xa.z, w4.z, a2.z); a2.w = fmaf(xa.z, w4.w, a2.w);
            a3.x = fmaf(xa.w, w4.x, a3.x); a3.y = fmaf(xa.w, w4.y, a3.y);
            a3.z = fmaf(xa.w, w4.z, a3.z); a3.w = fmaf(xa.w, w4.w, a3.w);
        }
        *reinterpret_cast<ushort4*>(&sv[0][i][k0]) =
            make_ushort4(f2bf(a0.x), f2bf(a0.y), f2bf(a0.z), f2bf(a0.w));
        *reinterpret_cast<ushort4*>(&sv[1][i][k0]) =
            make_ushort4(f2bf(a1.x), f2bf(a1.y), f2bf(a1.z), f2bf(a1.w));
        *reinterpret_cast<ushort4*>(&sv[2][i][k0]) =
            make_ushort4(f2bf(a2.x), f2bf(a2.y), f2bf(a2.z), f2bf(a2.w));
        *reinterpret_cast<ushort4*>(&sv[3][i][k0]) =
            make_ushort4(f2bf(a3.x), f2bf(a3.y), f2bf(a3.z), f2bf(a3.w));
    }

    const float2 b0 = *reinterpret_cast<const float2*>(bias + 2 * l);
    float2 b1 = make_float2(0.f, 0.f);
    if (l < 16) b1 = *reinterpret_cast<const float2*>(bias + 128 + 2 * l);

    float lg[NOD];
#pragma unroll
    for (int od = 0; od < NOD; ++od) lg[od] = 0.f;
    const int iown = l & 31;

    __syncthreads();

    for (int it = 0; it < NROUT; ++it) {
        {
            float m = lg[0];
#pragma unroll
            for (int od = 1; od < NOD; ++od) m = fmaxf(m, lg[od]);
            float e[NOD];
            float s = 0.f;
#pragma unroll
            for (int od = 0; od < NOD; ++od) { e[od] = __expf(lg[od] - m); s += e[od]; }
            const float inv = 1.f / s;
            if (l < 32) {
#pragma unroll
                for (int od = 0; od < NOD; ++od)
                    srt_f[(w * NOD + od) * 33 + iown] = e[od] * inv;
            }
        }
        __builtin_amdgcn_wave_barrier();
        {
            const int od0 = l >> 3;
            float a0 = b0.x, a1 = b0.y;
#pragma unroll
            for (int i = 0; i < NI; ++i) {
                const unsigned d = *reinterpret_cast<const unsigned*>(&sv[w][i][2 * l]);
                const float r = srt_f[(w * NOD + od0) * 33 + i];
                a0 = fmaf(r, bf_lo(d), a0);
                a1 = fmaf(r, bf_hi(d), a1);
            }
            float ss = a0 * a0 + a1 * a1;
            ss += __shfl_xor(ss, 1, 8);
            ss += __shfl_xor(ss, 2, 8);
            ss += __shfl_xor(ss, 4, 8);
            const float sc = sqrtf(ss) / (1.f + ss);
            *reinterpret_cast<float2*>(&sact_f[w * 164 + 2 * l]) = make_float2(a0 * sc, a1 * sc);
            if (l < 16) {
                const int od1 = 8 + (l >> 3);
                float c0 = b1.x, c1 = b1.y;
#pragma unroll
                for (int i = 0; i < NI; ++i) {
                    const unsigned d = *reinterpret_cast<const unsigned*>(&sv[w][i][128 + 2 * l]);
                    const float r = srt_f[(w * NOD + od1) * 33 + i];
                    c0 = fmaf(r, bf_lo(d), c0);
                    c1 = fmaf(r, bf_hi(d), c1);
                }
                float s2 = c0 * c0 + c1 * c1;
                s2 += __shfl_xor(s2, 1, 8);
                s2 += __shfl_xor(s2, 2, 8);
                s2 += __shfl_xor(s2, 4, 8);
                const float sc2 = sqrtf(s2) / (1.f + s2);
                *reinterpret_cast<float2*>(&sact_f[w * 164 + 128 + 2 * l]) =
                    make_float2(c0 * sc2, c1 * sc2);
            }
        }
        __builtin_amdgcn_wave_barrier();
        if (it < NROUT - 1) {
#pragma unroll
            for (int r = 0; r < 5; ++r) {
                const int t  = l + 64 * r;
                const int i  = t & 31;
                const int od = t >> 5;
                const uint4 d0 = *reinterpret_cast<const uint4*>(&sv[w][i][od * NOA]);
                const uint4 d1 = *reinterpret_cast<const uint4*>(&sv[w][i][od * NOA + 8]);
                const float* ap = &sact_f[w * 164 + od * NOA];
                const float4 c0 = *reinterpret_cast<const float4*>(ap + 0);
                const float4 c1 = *reinterpret_cast<const float4*>(ap + 4);
                const float4 c2 = *reinterpret_cast<const float4*>(ap + 8);
                const float4 c3 = *reinterpret_cast<const float4*>(ap + 12);
                float acc;
                acc  = bf_lo(d0.x) * c0.x;
                acc = fmaf(bf_hi(d0.x), c0.y, acc);
                acc = fmaf(bf_lo(d0.y), c0.z, acc);
                acc = fmaf(bf_hi(d0.y), c0.w, acc);
                acc = fmaf(bf_lo(d0.z), c1.x, acc);
                acc = fmaf(bf_hi(d0.z), c1.y, acc);
                acc = fmaf(bf_lo(d0.w), c1.z, acc);
                acc = fmaf(bf_hi(d0.w), c1.w, acc);
                acc = fmaf(bf_lo(d1.x), c2.x, acc);
                acc = fmaf(bf_hi(d1.x), c2.y, acc);
                acc = fmaf(bf_lo(d1.y), c2.z, acc);
                acc = fmaf(bf_hi(d1.y), c2.w, acc);
                acc = fmaf(bf_lo(d1.z), c3.x, acc);
                acc = fmaf(bf_hi(d1.z), c3.y, acc);
                acc = fmaf(bf_lo(d1.w), c3.z, acc);
                acc = fmaf(bf_hi(d1.w), c3.w, acc);
                srt_f[(w * NOD + od) * 33 + i] = acc;
            }
            __builtin_amdgcn_wave_barrier();
#pragma unroll
            for (int od = 0; od < NOD; ++od)
                lg[od] += srt_f[(w * NOD + od) * 33 + iown];
            __builtin_amdgcn_wave_barrier();
        }
    }

    __syncthreads();
    if (tid < NK) {
        const float4 v = make_float4(sact_f[0 * 164 + tid], sact_f[1 * 164 + tid],
                                     sact_f[2 * 164 + tid], sact_f[3 * 164 + tid]);
        *reinterpret_cast<float4*>(out + ((size_t)b * NK + tid) * NHW + hw0) = v;
    }
}

extern "C" void kernel_launch(void* const* d_in, const int* in_sizes, int n_in,
                              void* d_out, int out_size, void* d_ws, size_t ws_size,
                              hipStream_t stream) {
    const float* x      = (const float*)d_in[0];
    const float* weight = (const float*)d_in[1];
    const float* bias   = (const float*)d_in[2];
    float* out          = (float*)d_out;

    if (ws_size >= WS_NEEDED) {
        unsigned short* w_bf = (unsigned short*)d_ws;
        float* x_t = (float*)((char*)d_ws + XT_OFF);
        prepass_kernel<<<320 + NB * 72, 256, 0, stream>>>(x, weight, w_bf, x_t);
        capsule_fused5_kernel<<<NROWS / 4, 512, 0, stream>>>(x_t, w_bf, bias, out);
    } else {
        capsule_fused_kernel<<<NB * (NHW / 4), 256, 0, stream>>>(x, weight, bias, out);
    }
}